// Round 10
// baseline (8404.736 us; speedup 1.0000x reference)
//
#include <hip/hip_runtime.h>

#define B_   32
#define T_   2048
#define DIN  128
#define H_   256
#define DOUT 256

typedef float f32x4 __attribute__((ext_vector_type(4)));
typedef short bf16x8 __attribute__((ext_vector_type(8)));
typedef unsigned long long ull_t;

__device__ __forceinline__ unsigned short f2bf(float f) {
  unsigned int u = __builtin_bit_cast(unsigned int, f);
  u += 0x7FFFu + ((u >> 16) & 1u);              // round-to-nearest-even
  return (unsigned short)(u >> 16);
}
// unpack bf16 slot q (0..3) from a uint2 (q0|q1<<16, q2|q3<<16)
__device__ __forceinline__ float bfq(uint2 v, int q) {
  unsigned int u = (q & 2) ? v.y : v.x;
  u = (q & 1) ? (u & 0xFFFF0000u) : (u << 16);
  return __builtin_bit_cast(float, u);
}
__device__ __forceinline__ float sigm(float x) {
  return __builtin_amdgcn_rcpf(1.f + __expf(-x));
}

// ---------------- Kernel 1: G = x @ W + b (unchanged from R9) -------------
// Value gate[n][m] for (t,blk) goes to halfword
//   [((t*2+blk)*(2|1)+gate)*16 + (w*4+nt)]*256 + l*4 + q
// where n = w*64+nt*16+(l>>4)*4+q, m = l&15.
__global__ __launch_bounds__(256) void k_gates(
    const float* __restrict__ x,
    const float* __restrict__ Wz, const float* __restrict__ Wr,
    const float* __restrict__ Wh,
    const float* __restrict__ bz, const float* __restrict__ br,
    const float* __restrict__ bh,
    unsigned short* __restrict__ Gzr, unsigned short* __restrict__ Gh)
{
  __shared__ __align__(16) float sx[32][DIN];
  const int gate = blockIdx.y;
  const float* W = (gate == 0) ? Wz : (gate == 1) ? Wr : Wh;
  const float* bias = (gate == 0) ? bz : (gate == 1) ? br : bh;
  const int tg = blockIdx.x & 255;   // t-group
  const int bg = blockIdx.x >> 8;    // b-group 0..7
  const int t0 = tg * 8, b0 = bg * 4;
  const int tid = threadIdx.x;

  {
    const float4* x4 = (const float4*)x;
    float4* s4 = (float4*)&sx[0][0];
#pragma unroll
    for (int mm = 0; mm < 4; ++mm) {
      int idx = tid + 256 * mm;      // 0..1023
      int i = idx >> 5, c4 = idx & 31;
      int Ri = (b0 + (i >> 3)) * T_ + t0 + (i & 7);
      s4[idx] = x4[(size_t)Ri * 32 + c4];
    }
  }
  __syncthreads();

  const int j = tid;
  const float bj = bias[j];
  float acc[32];
#pragma unroll
  for (int i = 0; i < 32; ++i) acc[i] = 0.f;

#pragma unroll 2
  for (int k4 = 0; k4 < DIN / 4; ++k4) {
    float w0 = W[(size_t)(4 * k4 + 0) * H_ + j];
    float w1 = W[(size_t)(4 * k4 + 1) * H_ + j];
    float w2 = W[(size_t)(4 * k4 + 2) * H_ + j];
    float w3 = W[(size_t)(4 * k4 + 3) * H_ + j];
#pragma unroll
    for (int i = 0; i < 32; ++i) {
      float4 xv = *(const float4*)&sx[i][4 * k4];
      acc[i] = fmaf(xv.x, w0, acc[i]);
      acc[i] = fmaf(xv.y, w1, acc[i]);
      acc[i] = fmaf(xv.z, w2, acc[i]);
      acc[i] = fmaf(xv.w, w3, acc[i]);
    }
  }

  const int w = j >> 6, nt = (j >> 4) & 3, lq = (j >> 2) & 3, q = j & 3;
#pragma unroll
  for (int i = 0; i < 32; ++i) {
    int b = b0 + (i >> 3), t = t0 + (i & 7);
    int m = b & 15, blk = b >> 4;
    int l = lq * 16 + m;
    unsigned short v = f2bf(acc[i] + bj);
    if (gate < 2)
      Gzr[((((size_t)t * 2 + blk) * 2 + gate) * 16 + (w * 4 + nt)) * 256 + l * 4 + q] = v;
    else
      Gh[(((size_t)t * 2 + blk) * 16 + (w * 4 + nt)) * 256 + l * 4 + q] = v;
  }
}

// ---------------- Kernel 2: swapped-MFMA GRU scan (BUILTIN MFMAs) ----------
// 256 threads = 4 waves = 1 wave/SIMD -> 512-reg/thread unified budget.
// All three U matrices as Uᵀ A-fragments: 96 frags = 384 regs, "+a"-pinned
// once at init; BUILTIN mfma consumes them (AV-class operands, compiler
// handles all hazards — the R9 inline-asm hazard risk is removed).
// h/rh tiles [m][k] bf16 in LDS (16KB), streamed as B-fragments.
__global__
__attribute__((amdgpu_flat_work_group_size(256, 256), amdgpu_waves_per_eu(1, 1)))
void k_scan(
    const float* __restrict__ h0,
    const float* __restrict__ Uz, const float* __restrict__ Ur,
    const float* __restrict__ Uh,
    const uint2* __restrict__ Gzr, const uint2* __restrict__ Gh,
    float* __restrict__ hs)
{
  __shared__ __align__(16) unsigned short h_lds[16 * 256];   // [m][k], swz
  __shared__ __align__(16) unsigned short rh_lds[16 * 256];

  const int blk = blockIdx.x;        // 0..1
  const int tid = threadIdx.x;
  const int w = tid >> 6;            // wave 0..3, owns n in [64w, 64w+64)
  const int l = tid & 63;
  const int lm = l & 15;             // batch index m
  const int lk = l >> 4;             // k-group / n-quad group
  const int swz = (lm & 7) << 4;     // XOR swizzle (16B granularity)

  // ---- A-fragments of Uᵀ: frag[nt][kt], lane holds U[k0..k0+8)[n] ----
  bf16x8 fZ[4][8], fR[4][8], fH[4][8];
#pragma unroll
  for (int nt = 0; nt < 4; ++nt) {
    int n = w * 64 + nt * 16 + lm;
#pragma unroll
    for (int kt = 0; kt < 8; ++kt) {
      int k0 = kt * 32 + lk * 8;
      bf16x8 a, b, c;
#pragma unroll
      for (int e = 0; e < 8; ++e) {
        a[e] = (short)f2bf(Uz[(size_t)(k0 + e) * H_ + n]);
        b[e] = (short)f2bf(Ur[(size_t)(k0 + e) * H_ + n]);
        c[e] = (short)f2bf(Uh[(size_t)(k0 + e) * H_ + n]);
      }
      fZ[nt][kt] = a; fR[nt][kt] = b; fH[nt][kt] = c;
      asm volatile("" : "+a"(fZ[nt][kt]), "+a"(fR[nt][kt]), "+a"(fH[nt][kt]));
    }
  }

  // ---- init h-state: lane holds h[n = w*64+nt*16+lk*4+q][m = lm] ----
  float hreg[4][4];
#pragma unroll
  for (int nt = 0; nt < 4; ++nt) {
    int nb = w * 64 + nt * 16 + lk * 4;
    ull_t pk = 0;
#pragma unroll
    for (int q = 0; q < 4; ++q) {
      float h = h0[(size_t)(blk * 16 + lm) * H_ + nb + q];
      hreg[nt][q] = h;
      pk |= (ull_t)f2bf(h) << (16 * q);
    }
    *(ull_t*)((char*)h_lds + ((lm * 512 + nb * 2) ^ swz)) = pk;
  }
  __syncthreads();

  // ---- G: single-buffered, reloaded right after last use each step ----
  uint2 gz[4], gr[4], gh[4];
#pragma unroll
  for (int nt = 0; nt < 4; ++nt) {
    size_t slot = (size_t)(w * 4 + nt) * 64 + l;
    gz[nt] = Gzr[((size_t)blk * 2 + 0) * 1024 + slot];
    gr[nt] = Gzr[((size_t)blk * 2 + 1) * 1024 + slot];
    gh[nt] = Gh[(size_t)blk * 1024 + slot];
  }

  float* hsb = hs + (size_t)(blk * 16 + lm) * T_ * H_;
  const f32x4 zero4 = {0.f, 0.f, 0.f, 0.f};

#pragma unroll 1
  for (int t = 0; t < T_; ++t) {
    const int tn = (t + 1 < T_) ? (t + 1) : t;

    // ---- phase 1: zᵀ,rᵀ = [Uzᵀ|Urᵀ](AGPR A) @ hᵀ(LDS B) ----
    f32x4 az[4] = {zero4, zero4, zero4, zero4};
    f32x4 ar[4] = {zero4, zero4, zero4, zero4};
#pragma unroll
    for (int kt = 0; kt < 8; ++kt) {
      bf16x8 hb = *(const bf16x8*)((const char*)h_lds +
                                   ((lm * 512 + kt * 64 + lk * 16) ^ swz));
      az[0] = __builtin_amdgcn_mfma_f32_16x16x32_bf16(fZ[0][kt], hb, az[0], 0, 0, 0);
      az[1] = __builtin_amdgcn_mfma_f32_16x16x32_bf16(fZ[1][kt], hb, az[1], 0, 0, 0);
      az[2] = __builtin_amdgcn_mfma_f32_16x16x32_bf16(fZ[2][kt], hb, az[2], 0, 0, 0);
      az[3] = __builtin_amdgcn_mfma_f32_16x16x32_bf16(fZ[3][kt], hb, az[3], 0, 0, 0);
      ar[0] = __builtin_amdgcn_mfma_f32_16x16x32_bf16(fR[0][kt], hb, ar[0], 0, 0, 0);
      ar[1] = __builtin_amdgcn_mfma_f32_16x16x32_bf16(fR[1][kt], hb, ar[1], 0, 0, 0);
      ar[2] = __builtin_amdgcn_mfma_f32_16x16x32_bf16(fR[2][kt], hb, ar[2], 0, 0, 0);
      ar[3] = __builtin_amdgcn_mfma_f32_16x16x32_bf16(fR[3][kt], hb, ar[3], 0, 0, 0);
    }

    // ---- epilogue 1: z kept in az regs; rh packed -> rh_lds (b64) ----
#pragma unroll
    for (int nt = 0; nt < 4; ++nt) {
      int nb = w * 64 + nt * 16 + lk * 4;
      ull_t pk = 0;
#pragma unroll
      for (int q = 0; q < 4; ++q) {
        float zf = sigm(az[nt][q] + bfq(gz[nt], q));
        float rf = sigm(ar[nt][q] + bfq(gr[nt], q));
        az[nt][q] = zf;                            // z survives to epilogue 2
        pk |= (ull_t)f2bf(rf * hreg[nt][q]) << (16 * q);
      }
      *(ull_t*)((char*)rh_lds + ((lm * 512 + nb * 2) ^ swz)) = pk;
      size_t slot = (size_t)(w * 4 + nt) * 64 + l;
      gz[nt] = Gzr[(((size_t)tn * 2 + blk) * 2 + 0) * 1024 + slot];
      gr[nt] = Gzr[(((size_t)tn * 2 + blk) * 2 + 1) * 1024 + slot];
    }
    __syncthreads();

    // ---- phase 2: hhᵀ = Uhᵀ(AGPR A) @ rhᵀ(LDS B) ----
    f32x4 ah[4] = {zero4, zero4, zero4, zero4};
#pragma unroll
    for (int kt = 0; kt < 8; ++kt) {
      bf16x8 rb = *(const bf16x8*)((const char*)rh_lds +
                                   ((lm * 512 + kt * 64 + lk * 16) ^ swz));
      ah[0] = __builtin_amdgcn_mfma_f32_16x16x32_bf16(fH[0][kt], rb, ah[0], 0, 0, 0);
      ah[1] = __builtin_amdgcn_mfma_f32_16x16x32_bf16(fH[1][kt], rb, ah[1], 0, 0, 0);
      ah[2] = __builtin_amdgcn_mfma_f32_16x16x32_bf16(fH[2][kt], rb, ah[2], 0, 0, 0);
      ah[3] = __builtin_amdgcn_mfma_f32_16x16x32_bf16(fH[3][kt], rb, ah[3], 0, 0, 0);
    }

    // ---- epilogue 2: tanh, blend, write h_lds (b64) + hs (float4) ----
#pragma unroll
    for (int nt = 0; nt < 4; ++nt) {
      int nb = w * 64 + nt * 16 + lk * 4;
      f32x4 hv;
      ull_t pk = 0;
#pragma unroll
      for (int q = 0; q < 4; ++q) {
        float xh = ah[nt][q] + bfq(gh[nt], q);
        float e = __expf(-2.f * xh);
        float hh = 2.f * __builtin_amdgcn_rcpf(1.f + e) - 1.f;   // tanh
        float z = az[nt][q];
        float h = hreg[nt][q];
        float hn = h + z * (hh - h);
        hreg[nt][q] = hn;
        hv[q] = hn;
        pk |= (ull_t)f2bf(hn) << (16 * q);
      }
      *(ull_t*)((char*)h_lds + ((lm * 512 + nb * 2) ^ swz)) = pk;
      *(f32x4*)&hsb[(size_t)t * H_ + nb] = hv;
      gh[nt] = Gh[((size_t)tn * 2 + blk) * 1024 + (size_t)(w * 4 + nt) * 64 + l];
    }
    __syncthreads();
  }
}

// ---------------- Kernel 3: ys = hs @ Wo + bo ------------------------------
__global__ __launch_bounds__(256) void k_out(
    const float* __restrict__ hs, const float* __restrict__ Wo,
    const float* __restrict__ bo, float* __restrict__ ys)
{
  __shared__ __align__(16) float sh[32][H_];
  const int row0 = blockIdx.x * 32;
  const int tid = threadIdx.x;

  const float4* hg = (const float4*)(hs + (size_t)row0 * H_);
  float4* sh4 = (float4*)&sh[0][0];
#pragma unroll
  for (int m = 0; m < 8; ++m) sh4[tid + 256 * m] = hg[tid + 256 * m];
  __syncthreads();

  const int j = tid;
  float acc[32];
#pragma unroll
  for (int i = 0; i < 32; ++i) acc[i] = 0.f;

#pragma unroll 2
  for (int k4 = 0; k4 < H_ / 4; ++k4) {
    float w0 = Wo[(size_t)(4 * k4 + 0) * DOUT + j];
    float w1 = Wo[(size_t)(4 * k4 + 1) * DOUT + j];
    float w2 = Wo[(size_t)(4 * k4 + 2) * DOUT + j];
    float w3 = Wo[(size_t)(4 * k4 + 3) * DOUT + j];
#pragma unroll
    for (int i = 0; i < 32; ++i) {
      float4 hv = *(const float4*)&sh[i][4 * k4];
      acc[i] = fmaf(hv.x, w0, acc[i]);
      acc[i] = fmaf(hv.y, w1, acc[i]);
      acc[i] = fmaf(hv.z, w2, acc[i]);
      acc[i] = fmaf(hv.w, w3, acc[i]);
    }
  }

  const float bj = bo[j];
  float* yp = ys + (size_t)row0 * DOUT + j;
#pragma unroll
  for (int i = 0; i < 32; ++i) yp[(size_t)i * DOUT] = acc[i] + bj;
}

// ---------------------------------------------------------------------------
extern "C" void kernel_launch(void* const* d_in, const int* in_sizes, int n_in,
                              void* d_out, int out_size, void* d_ws, size_t ws_size,
                              hipStream_t stream) {
  const float* x  = (const float*)d_in[0];
  const float* h0 = (const float*)d_in[1];
  const float* Wz = (const float*)d_in[2];
  const float* Uz = (const float*)d_in[3];
  const float* bz = (const float*)d_in[4];
  const float* Wr = (const float*)d_in[5];
  const float* Ur = (const float*)d_in[6];
  const float* br = (const float*)d_in[7];
  const float* Wh = (const float*)d_in[8];
  const float* Uh = (const float*)d_in[9];
  const float* bh = (const float*)d_in[10];
  const float* Wo = (const float*)d_in[11];
  const float* bo = (const float*)d_in[12];

  float* ys = (float*)d_out;
  float* hsO = ys + (size_t)B_ * T_ * DOUT;  // second output, written by scan

  unsigned short* Gzr = (unsigned short*)d_out;   // 64 MB, dead until k_out
  unsigned short* Gh  = (unsigned short*)d_ws;    // 32 MB in workspace

  dim3 g1(2048, 3);                          // 256 t-groups x 8 b-groups, 3 gates
  k_gates<<<g1, 256, 0, stream>>>(x, Wz, Wr, Wh, bz, br, bh, Gzr, Gh);
  k_scan<<<2, 256, 0, stream>>>(h0, Uz, Ur, Uh, (const uint2*)Gzr, (const uint2*)Gh, hsO);
  k_out<<<(B_ * T_) / 32, 256, 0, stream>>>(hsO, Wo, bo, ys);
}

// Round 11
// 6061.919 us; speedup vs baseline: 1.3865x; 1.3865x over previous
//
#include <hip/hip_runtime.h>

#define B_   32
#define T_   2048
#define DIN  128
#define H_   256
#define DOUT 256

typedef float f32x4 __attribute__((ext_vector_type(4)));
typedef short bf16x8 __attribute__((ext_vector_type(8)));
typedef unsigned long long ull_t;

__device__ __forceinline__ unsigned short f2bf(float f) {
  unsigned int u = __builtin_bit_cast(unsigned int, f);
  u += 0x7FFFu + ((u >> 16) & 1u);              // round-to-nearest-even
  return (unsigned short)(u >> 16);
}
// unpack bf16 slot q (0..3) from a uint2 (q0|q1<<16, q2|q3<<16)
__device__ __forceinline__ float bfq(uint2 v, int q) {
  unsigned int u = (q & 2) ? v.y : v.x;
  u = (q & 1) ? (u & 0xFFFF0000u) : (u << 16);
  return __builtin_bit_cast(float, u);
}
__device__ __forceinline__ float sigm(float x) {
  return __builtin_amdgcn_rcpf(1.f + __expf(-x));
}

// ---------------- Kernel 1: G = x @ W + b (unchanged — validated R10) ------
// Value gate[n][m] for (t,blk) goes to halfword
//   [((t*2+blk)*(2|1)+gate)*16 + (w*4+nt)]*256 + l*4 + q
// where n = w*64+nt*16+(l>>4)*4+q, m = l&15.
__global__ __launch_bounds__(256) void k_gates(
    const float* __restrict__ x,
    const float* __restrict__ Wz, const float* __restrict__ Wr,
    const float* __restrict__ Wh,
    const float* __restrict__ bz, const float* __restrict__ br,
    const float* __restrict__ bh,
    unsigned short* __restrict__ Gzr, unsigned short* __restrict__ Gh)
{
  __shared__ __align__(16) float sx[32][DIN];
  const int gate = blockIdx.y;
  const float* W = (gate == 0) ? Wz : (gate == 1) ? Wr : Wh;
  const float* bias = (gate == 0) ? bz : (gate == 1) ? br : bh;
  const int tg = blockIdx.x & 255;   // t-group
  const int bg = blockIdx.x >> 8;    // b-group 0..7
  const int t0 = tg * 8, b0 = bg * 4;
  const int tid = threadIdx.x;

  {
    const float4* x4 = (const float4*)x;
    float4* s4 = (float4*)&sx[0][0];
#pragma unroll
    for (int mm = 0; mm < 4; ++mm) {
      int idx = tid + 256 * mm;      // 0..1023
      int i = idx >> 5, c4 = idx & 31;
      int Ri = (b0 + (i >> 3)) * T_ + t0 + (i & 7);
      s4[idx] = x4[(size_t)Ri * 32 + c4];
    }
  }
  __syncthreads();

  const int j = tid;
  const float bj = bias[j];
  float acc[32];
#pragma unroll
  for (int i = 0; i < 32; ++i) acc[i] = 0.f;

#pragma unroll 2
  for (int k4 = 0; k4 < DIN / 4; ++k4) {
    float w0 = W[(size_t)(4 * k4 + 0) * H_ + j];
    float w1 = W[(size_t)(4 * k4 + 1) * H_ + j];
    float w2 = W[(size_t)(4 * k4 + 2) * H_ + j];
    float w3 = W[(size_t)(4 * k4 + 3) * H_ + j];
#pragma unroll
    for (int i = 0; i < 32; ++i) {
      float4 xv = *(const float4*)&sx[i][4 * k4];
      acc[i] = fmaf(xv.x, w0, acc[i]);
      acc[i] = fmaf(xv.y, w1, acc[i]);
      acc[i] = fmaf(xv.z, w2, acc[i]);
      acc[i] = fmaf(xv.w, w3, acc[i]);
    }
  }

  const int w = j >> 6, nt = (j >> 4) & 3, lq = (j >> 2) & 3, q = j & 3;
#pragma unroll
  for (int i = 0; i < 32; ++i) {
    int b = b0 + (i >> 3), t = t0 + (i & 7);
    int m = b & 15, blk = b >> 4;
    int l = lq * 16 + m;
    unsigned short v = f2bf(acc[i] + bj);
    if (gate < 2)
      Gzr[((((size_t)t * 2 + blk) * 2 + gate) * 16 + (w * 4 + nt)) * 256 + l * 4 + q] = v;
    else
      Gh[(((size_t)t * 2 + blk) * 16 + (w * 4 + nt)) * 256 + l * 4 + q] = v;
  }
}

// ---------------- Kernel 2: swapped-MFMA GRU scan (R10 + legal reg budget) -
// 256 threads = 4 waves = 1 wave/SIMD -> 512-reg unified budget (pool is
// 512/SIMD; m69). AGPR cap is 256: ONLY fZ+fR are "a"-pinned (exactly 256
// AGPRs, read in place by MFMA). fH lives in arch VGPRs (128) + ~100 working
// = 228 <= 256 arch. Total unified 484 <= 512 -> spill-free by construction.
__global__
__attribute__((amdgpu_flat_work_group_size(256, 256), amdgpu_waves_per_eu(1, 1)))
void k_scan(
    const float* __restrict__ h0,
    const float* __restrict__ Uz, const float* __restrict__ Ur,
    const float* __restrict__ Uh,
    const uint2* __restrict__ Gzr, const uint2* __restrict__ Gh,
    float* __restrict__ hs)
{
  __shared__ __align__(16) unsigned short h_lds[16 * 256];   // [m][k], swz
  __shared__ __align__(16) unsigned short rh_lds[16 * 256];

  const int blk = blockIdx.x;        // 0..1
  const int tid = threadIdx.x;
  const int w = tid >> 6;            // wave 0..3, owns n in [64w, 64w+64)
  const int l = tid & 63;
  const int lm = l & 15;             // batch index m
  const int lk = l >> 4;             // k-group / n-quad group
  const int swz = (lm & 7) << 4;     // XOR swizzle (16B granularity)

  // ---- A-fragments of Uᵀ: frag[nt][kt], lane holds U[k0..k0+8)[n] ----
  bf16x8 fZ[4][8], fR[4][8], fH[4][8];
#pragma unroll
  for (int nt = 0; nt < 4; ++nt) {
    int n = w * 64 + nt * 16 + lm;
#pragma unroll
    for (int kt = 0; kt < 8; ++kt) {
      int k0 = kt * 32 + lk * 8;
      bf16x8 a, b, c;
#pragma unroll
      for (int e = 0; e < 8; ++e) {
        a[e] = (short)f2bf(Uz[(size_t)(k0 + e) * H_ + n]);
        b[e] = (short)f2bf(Ur[(size_t)(k0 + e) * H_ + n]);
        c[e] = (short)f2bf(Uh[(size_t)(k0 + e) * H_ + n]);
      }
      fZ[nt][kt] = a; fR[nt][kt] = b; fH[nt][kt] = c;
      // Pin ONLY fZ,fR into AGPRs (2*4*8*4 = 256 = the full AGPR file).
      // fH stays in arch VGPRs -> total unified 484 <= 512, no spill.
      asm volatile("" : "+a"(fZ[nt][kt]), "+a"(fR[nt][kt]));
    }
  }

  // ---- init h-state: lane holds h[n = w*64+nt*16+lk*4+q][m = lm] ----
  float hreg[4][4];
#pragma unroll
  for (int nt = 0; nt < 4; ++nt) {
    int nb = w * 64 + nt * 16 + lk * 4;
    ull_t pk = 0;
#pragma unroll
    for (int q = 0; q < 4; ++q) {
      float h = h0[(size_t)(blk * 16 + lm) * H_ + nb + q];
      hreg[nt][q] = h;
      pk |= (ull_t)f2bf(h) << (16 * q);
    }
    *(ull_t*)((char*)h_lds + ((lm * 512 + nb * 2) ^ swz)) = pk;
  }
  __syncthreads();

  // ---- G: single-buffered, reloaded right after last use each step ----
  uint2 gz[4], gr[4], gh[4];
#pragma unroll
  for (int nt = 0; nt < 4; ++nt) {
    size_t slot = (size_t)(w * 4 + nt) * 64 + l;
    gz[nt] = Gzr[((size_t)blk * 2 + 0) * 1024 + slot];
    gr[nt] = Gzr[((size_t)blk * 2 + 1) * 1024 + slot];
    gh[nt] = Gh[(size_t)blk * 1024 + slot];
  }

  float* hsb = hs + (size_t)(blk * 16 + lm) * T_ * H_;
  const f32x4 zero4 = {0.f, 0.f, 0.f, 0.f};

#pragma unroll 1
  for (int t = 0; t < T_; ++t) {
    const int tn = (t + 1 < T_) ? (t + 1) : t;

    // ---- phase 1: zᵀ,rᵀ = [Uzᵀ|Urᵀ](AGPR A) @ hᵀ(LDS B) ----
    f32x4 az[4] = {zero4, zero4, zero4, zero4};
    f32x4 ar[4] = {zero4, zero4, zero4, zero4};
#pragma unroll
    for (int kt = 0; kt < 8; ++kt) {
      bf16x8 hb = *(const bf16x8*)((const char*)h_lds +
                                   ((lm * 512 + kt * 64 + lk * 16) ^ swz));
      az[0] = __builtin_amdgcn_mfma_f32_16x16x32_bf16(fZ[0][kt], hb, az[0], 0, 0, 0);
      az[1] = __builtin_amdgcn_mfma_f32_16x16x32_bf16(fZ[1][kt], hb, az[1], 0, 0, 0);
      az[2] = __builtin_amdgcn_mfma_f32_16x16x32_bf16(fZ[2][kt], hb, az[2], 0, 0, 0);
      az[3] = __builtin_amdgcn_mfma_f32_16x16x32_bf16(fZ[3][kt], hb, az[3], 0, 0, 0);
      ar[0] = __builtin_amdgcn_mfma_f32_16x16x32_bf16(fR[0][kt], hb, ar[0], 0, 0, 0);
      ar[1] = __builtin_amdgcn_mfma_f32_16x16x32_bf16(fR[1][kt], hb, ar[1], 0, 0, 0);
      ar[2] = __builtin_amdgcn_mfma_f32_16x16x32_bf16(fR[2][kt], hb, ar[2], 0, 0, 0);
      ar[3] = __builtin_amdgcn_mfma_f32_16x16x32_bf16(fR[3][kt], hb, ar[3], 0, 0, 0);
    }

    // ---- epilogue 1: z kept in az regs; rh packed -> rh_lds (b64) ----
#pragma unroll
    for (int nt = 0; nt < 4; ++nt) {
      int nb = w * 64 + nt * 16 + lk * 4;
      ull_t pk = 0;
#pragma unroll
      for (int q = 0; q < 4; ++q) {
        float zf = sigm(az[nt][q] + bfq(gz[nt], q));
        float rf = sigm(ar[nt][q] + bfq(gr[nt], q));
        az[nt][q] = zf;                            // z survives to epilogue 2
        pk |= (ull_t)f2bf(rf * hreg[nt][q]) << (16 * q);
      }
      *(ull_t*)((char*)rh_lds + ((lm * 512 + nb * 2) ^ swz)) = pk;
      size_t slot = (size_t)(w * 4 + nt) * 64 + l;
      gz[nt] = Gzr[(((size_t)tn * 2 + blk) * 2 + 0) * 1024 + slot];
      gr[nt] = Gzr[(((size_t)tn * 2 + blk) * 2 + 1) * 1024 + slot];
    }
    __syncthreads();

    // ---- phase 2: hhᵀ = Uhᵀ(VGPR A) @ rhᵀ(LDS B) ----
    f32x4 ah[4] = {zero4, zero4, zero4, zero4};
#pragma unroll
    for (int kt = 0; kt < 8; ++kt) {
      bf16x8 rb = *(const bf16x8*)((const char*)rh_lds +
                                   ((lm * 512 + kt * 64 + lk * 16) ^ swz));
      ah[0] = __builtin_amdgcn_mfma_f32_16x16x32_bf16(fH[0][kt], rb, ah[0], 0, 0, 0);
      ah[1] = __builtin_amdgcn_mfma_f32_16x16x32_bf16(fH[1][kt], rb, ah[1], 0, 0, 0);
      ah[2] = __builtin_amdgcn_mfma_f32_16x16x32_bf16(fH[2][kt], rb, ah[2], 0, 0, 0);
      ah[3] = __builtin_amdgcn_mfma_f32_16x16x32_bf16(fH[3][kt], rb, ah[3], 0, 0, 0);
    }

    // ---- epilogue 2: tanh, blend, write h_lds (b64) + hs (float4) ----
#pragma unroll
    for (int nt = 0; nt < 4; ++nt) {
      int nb = w * 64 + nt * 16 + lk * 4;
      f32x4 hv;
      ull_t pk = 0;
#pragma unroll
      for (int q = 0; q < 4; ++q) {
        float xh = ah[nt][q] + bfq(gh[nt], q);
        float e = __expf(-2.f * xh);
        float hh = 2.f * __builtin_amdgcn_rcpf(1.f + e) - 1.f;   // tanh
        float z = az[nt][q];
        float h = hreg[nt][q];
        float hn = h + z * (hh - h);
        hreg[nt][q] = hn;
        hv[q] = hn;
        pk |= (ull_t)f2bf(hn) << (16 * q);
      }
      *(ull_t*)((char*)h_lds + ((lm * 512 + nb * 2) ^ swz)) = pk;
      *(f32x4*)&hsb[(size_t)t * H_ + nb] = hv;
      gh[nt] = Gh[((size_t)tn * 2 + blk) * 1024 + (size_t)(w * 4 + nt) * 64 + l];
    }
    __syncthreads();
  }
}

// ---------------- Kernel 3: ys = hs @ Wo + bo ------------------------------
__global__ __launch_bounds__(256) void k_out(
    const float* __restrict__ hs, const float* __restrict__ Wo,
    const float* __restrict__ bo, float* __restrict__ ys)
{
  __shared__ __align__(16) float sh[32][H_];
  const int row0 = blockIdx.x * 32;
  const int tid = threadIdx.x;

  const float4* hg = (const float4*)(hs + (size_t)row0 * H_);
  float4* sh4 = (float4*)&sh[0][0];
#pragma unroll
  for (int m = 0; m < 8; ++m) sh4[tid + 256 * m] = hg[tid + 256 * m];
  __syncthreads();

  const int j = tid;
  float acc[32];
#pragma unroll
  for (int i = 0; i < 32; ++i) acc[i] = 0.f;

#pragma unroll 2
  for (int k4 = 0; k4 < H_ / 4; ++k4) {
    float w0 = Wo[(size_t)(4 * k4 + 0) * DOUT + j];
    float w1 = Wo[(size_t)(4 * k4 + 1) * DOUT + j];
    float w2 = Wo[(size_t)(4 * k4 + 2) * DOUT + j];
    float w3 = Wo[(size_t)(4 * k4 + 3) * DOUT + j];
#pragma unroll
    for (int i = 0; i < 32; ++i) {
      float4 hv = *(const float4*)&sh[i][4 * k4];
      acc[i] = fmaf(hv.x, w0, acc[i]);
      acc[i] = fmaf(hv.y, w1, acc[i]);
      acc[i] = fmaf(hv.z, w2, acc[i]);
      acc[i] = fmaf(hv.w, w3, acc[i]);
    }
  }

  const float bj = bo[j];
  float* yp = ys + (size_t)row0 * DOUT + j;
#pragma unroll
  for (int i = 0; i < 32; ++i) yp[(size_t)i * DOUT] = acc[i] + bj;
}

// ---------------------------------------------------------------------------
extern "C" void kernel_launch(void* const* d_in, const int* in_sizes, int n_in,
                              void* d_out, int out_size, void* d_ws, size_t ws_size,
                              hipStream_t stream) {
  const float* x  = (const float*)d_in[0];
  const float* h0 = (const float*)d_in[1];
  const float* Wz = (const float*)d_in[2];
  const float* Uz = (const float*)d_in[3];
  const float* bz = (const float*)d_in[4];
  const float* Wr = (const float*)d_in[5];
  const float* Ur = (const float*)d_in[6];
  const float* br = (const float*)d_in[7];
  const float* Wh = (const float*)d_in[8];
  const float* Uh = (const float*)d_in[9];
  const float* bh = (const float*)d_in[10];
  const float* Wo = (const float*)d_in[11];
  const float* bo = (const float*)d_in[12];

  float* ys = (float*)d_out;
  float* hsO = ys + (size_t)B_ * T_ * DOUT;  // second output, written by scan

  unsigned short* Gzr = (unsigned short*)d_out;   // 64 MB, dead until k_out
  unsigned short* Gh  = (unsigned short*)d_ws;    // 32 MB in workspace

  dim3 g1(2048, 3);                          // 256 t-groups x 8 b-groups, 3 gates
  k_gates<<<g1, 256, 0, stream>>>(x, Wz, Wr, Wh, bz, br, bh, Gzr, Gh);
  k_scan<<<2, 256, 0, stream>>>(h0, Uz, Ur, Uh, (const uint2*)Gzr, (const uint2*)Gh, hsO);
  k_out<<<(B_ * T_) / 32, 256, 0, stream>>>(hsO, Wo, bo, ys);
}